// Round 1
// baseline (2244.032 us; speedup 1.0000x reference)
//
#include <hip/hip_runtime.h>

// GCN 2-layer forward for MI355X.
// out = D^-1/2 (A+I) D^-1/2 (X W) + b, twice, relu between.
// Refactor: g = (X W) * dinv ; tmp = g (self-loop) + scatter_add(g[row] -> col) ;
//           out = tmp * dinv + b.

constexpr int KD = 128;  // inner dim of both GEMMs (Fin = Fh = 128)

__global__ __launch_bounds__(256) void init_deg(float* deg, int N) {
    int i = blockIdx.x * 256 + threadIdx.x;
    if (i < N) deg[i] = 1.0f;  // self-loop
}

__global__ __launch_bounds__(256) void count_deg(const int* __restrict__ col,
                                                 float* deg, int E) {
    int i = blockIdx.x * 256 + threadIdx.x;
    if (i < E) atomicAdd(&deg[col[i]], 1.0f);
}

__global__ __launch_bounds__(256) void rsqrt_inplace(float* deg, int N) {
    int i = blockIdx.x * 256 + threadIdx.x;
    if (i < N) deg[i] = rsqrtf(deg[i]);
}

// G[n, :] = dinv[n] * (X[n, :] @ W)   (X: [N,128], W: [128,FOUT])
template <int FOUT>
__global__ __launch_bounds__(256) void gemm_scale(const float* __restrict__ X,
                                                  const float* __restrict__ W,
                                                  const float* __restrict__ dinv,
                                                  float* __restrict__ G, int N) {
    constexpr int ROWS = 32;
    constexpr int CT = FOUT / 4;     // threads along columns (each does 4 cols)
    constexpr int RT = 256 / CT;     // threads along rows
    constexpr int RPT = ROWS / RT;   // rows per thread
    __shared__ float Ws[KD][FOUT];   // 64KB (FOUT=128) or 32KB (FOUT=64)
    __shared__ float Xs[ROWS][KD];   // 16KB

    int t = threadIdx.x;
    int row0 = blockIdx.x * ROWS;

    const float4* W4 = (const float4*)W;
    float4* Ws4 = (float4*)&Ws[0][0];
    for (int i = t; i < KD * FOUT / 4; i += 256) Ws4[i] = W4[i];

    const float4* X4 = (const float4*)X;
    float4* Xs4 = (float4*)&Xs[0][0];
    int nf4 = N * (KD / 4);
    for (int i = t; i < ROWS * KD / 4; i += 256) {
        int gi = row0 * (KD / 4) + i;
        Xs4[i] = (gi < nf4) ? X4[gi] : make_float4(0.f, 0.f, 0.f, 0.f);
    }
    __syncthreads();

    int ct = t % CT;
    int rt = t / CT;
    int c0 = ct * 4;
    float acc[RPT][4] = {};
#pragma unroll 4
    for (int k = 0; k < KD; ++k) {
        float4 wv = *(const float4*)&Ws[k][c0];
#pragma unroll
        for (int r = 0; r < RPT; ++r) {
            float xv = Xs[rt * RPT + r][k];
            acc[r][0] += xv * wv.x;
            acc[r][1] += xv * wv.y;
            acc[r][2] += xv * wv.z;
            acc[r][3] += xv * wv.w;
        }
    }
#pragma unroll
    for (int r = 0; r < RPT; ++r) {
        int row = row0 + rt * RPT + r;
        if (row < N) {
            float s = dinv[row];
            float4 o = make_float4(acc[r][0] * s, acc[r][1] * s,
                                   acc[r][2] * s, acc[r][3] * s);
            *(float4*)&G[(size_t)row * FOUT + c0] = o;
        }
    }
}

__global__ __launch_bounds__(256) void copy4(const float* __restrict__ src,
                                             float* __restrict__ dst, int nf4) {
    int i = blockIdx.x * 256 + threadIdx.x;
    if (i < nf4) ((float4*)dst)[i] = ((const float4*)src)[i];
}

// For each edge e and feature quad q: T[col[e]][4q..4q+3] += G[row[e]][4q..4q+3]
template <int F>
__global__ __launch_bounds__(256) void scatter_add(const int* __restrict__ row,
                                                   const int* __restrict__ col,
                                                   const float* __restrict__ G,
                                                   float* __restrict__ T, int E) {
    constexpr int Q = F / 4;
    int i = blockIdx.x * 256 + threadIdx.x;
    if (i >= E * Q) return;
    int e = i / Q;        // pow2 -> shift
    int q = i % Q;
    int r = row[e];
    int c = col[e];
    float4 v = ((const float4*)G)[(size_t)r * Q + q];
    float* dst = T + (size_t)c * F + q * 4;
    atomicAdd(dst + 0, v.x);
    atomicAdd(dst + 1, v.y);
    atomicAdd(dst + 2, v.z);
    atomicAdd(dst + 3, v.w);
}

// O[n,f] = act(T[n,f] * dinv[n] + b[f])
template <int F, bool RELU>
__global__ __launch_bounds__(256) void finalize(const float* __restrict__ T,
                                                const float* __restrict__ dinv,
                                                const float* __restrict__ b,
                                                float* __restrict__ O, int N) {
    constexpr int Q = F / 4;
    int i = blockIdx.x * 256 + threadIdx.x;
    if (i >= N * Q) return;
    int node = i / Q;
    int q = i % Q;
    float s = dinv[node];
    float4 v = ((const float4*)T)[i];
    float4 bv = ((const float4*)b)[q];
    v.x = v.x * s + bv.x;
    v.y = v.y * s + bv.y;
    v.z = v.z * s + bv.z;
    v.w = v.w * s + bv.w;
    if (RELU) {
        v.x = fmaxf(v.x, 0.f);
        v.y = fmaxf(v.y, 0.f);
        v.z = fmaxf(v.z, 0.f);
        v.w = fmaxf(v.w, 0.f);
    }
    ((float4*)O)[i] = v;
}

extern "C" void kernel_launch(void* const* d_in, const int* in_sizes, int n_in,
                              void* d_out, int out_size, void* d_ws, size_t ws_size,
                              hipStream_t stream) {
    const float* x  = (const float*)d_in[0];
    const int*   ei = (const int*)d_in[1];   // int32 (JAX default x64-disabled)
    const float* W1 = (const float*)d_in[2];
    const float* b1 = (const float*)d_in[3];
    const float* W2 = (const float*)d_in[4];
    const float* b2 = (const float*)d_in[5];
    float* out = (float*)d_out;

    int N = in_sizes[0] / 128;
    int E = in_sizes[1] / 2;
    const int* row = ei;       // edge_index[0]
    const int* col = ei + E;   // edge_index[1]

    char* ws = (char*)d_ws;
    float* dinv = (float*)ws;                                  // N floats
    float* bufA = (float*)(ws + (size_t)(1u << 20));           // N*128 floats
    float* bufB = (float*)(ws + (size_t)(1u << 20) + (size_t)(28u << 20));

    int nb;
    nb = (N + 255) / 256; init_deg<<<nb, 256, 0, stream>>>(dinv, N);
    nb = (E + 255) / 256; count_deg<<<nb, 256, 0, stream>>>(col, dinv, E);
    nb = (N + 255) / 256; rsqrt_inplace<<<nb, 256, 0, stream>>>(dinv, N);

    // ---- layer 1 (F=128, relu) ----
    nb = (N + 31) / 32;
    gemm_scale<128><<<nb, 256, 0, stream>>>(x, W1, dinv, bufA, N);  // g1 = bufA
    int nf4 = N * 32;
    nb = (nf4 + 255) / 256;
    copy4<<<nb, 256, 0, stream>>>(bufA, bufB, nf4);                 // tmp1 = g1 (self-loop)
    int st = E * 32;
    nb = (st + 255) / 256;
    scatter_add<128><<<nb, 256, 0, stream>>>(row, col, bufA, bufB, E);
    nb = (nf4 + 255) / 256;
    finalize<128, true><<<nb, 256, 0, stream>>>(bufB, dinv, b1, bufA, N);  // h2 = bufA

    // ---- layer 2 (F=64, no relu) ----
    nb = (N + 31) / 32;
    gemm_scale<64><<<nb, 256, 0, stream>>>(bufA, W2, dinv, bufB, N);  // g2 = bufB
    int nf4b = N * 16;
    nb = (nf4b + 255) / 256;
    copy4<<<nb, 256, 0, stream>>>(bufB, bufA, nf4b);                  // tmp2 = bufA
    st = E * 16;
    nb = (st + 255) / 256;
    scatter_add<64><<<nb, 256, 0, stream>>>(row, col, bufB, bufA, E);
    nb = (nf4b + 255) / 256;
    finalize<64, false><<<nb, 256, 0, stream>>>(bufA, dinv, b2, out, N);
}

// Round 2
// 428.204 us; speedup vs baseline: 5.2406x; 5.2406x over previous
//
#include <hip/hip_runtime.h>

// GCN 2-layer forward for MI355X.
// out = D^-1/2 (A+I) D^-1/2 (X W) + b, twice, relu between.
// g = (X W) * dinv ; tmp[c] = g[c] + sum_{e: col_e=c} g[row_e] ; out = tmp*dinv + b.
// R2: CSR gather (no fp32 atomics). CSR built per-call: histogram -> scan -> fill.

constexpr int KD = 128;  // inner dim of both GEMMs (Fin = Fh = 128)

// ---------------- CSR build ----------------

__global__ __launch_bounds__(256) void hist_zero(int* cnt, int N) {
    int i = blockIdx.x * 256 + threadIdx.x;
    if (i < N) cnt[i] = 0;
}

__global__ __launch_bounds__(256) void hist(const int* __restrict__ col, int* cnt, int E) {
    int i = blockIdx.x * 256 + threadIdx.x;
    if (i < E) atomicAdd(&cnt[col[i]], 1);
}

// Single-block chunked exclusive scan: rowptr[0..N], cursor copy, dinv = rsqrt(1+cnt).
__global__ __launch_bounds__(1024) void scan_and_dinv(const int* __restrict__ cnt,
                                                      int* __restrict__ rowptr,
                                                      int* __restrict__ cursor,
                                                      float* __restrict__ dinv, int N) {
    __shared__ int smem[1024];
    __shared__ int carry;
    if (threadIdx.x == 0) carry = 0;
    __syncthreads();
    for (int base = 0; base < N; base += 1024) {
        int i = base + threadIdx.x;
        int v = (i < N) ? cnt[i] : 0;
        smem[threadIdx.x] = v;
        __syncthreads();
        for (int off = 1; off < 1024; off <<= 1) {
            int t = (threadIdx.x >= off) ? smem[threadIdx.x - off] : 0;
            __syncthreads();
            smem[threadIdx.x] += t;
            __syncthreads();
        }
        int incl = smem[threadIdx.x];
        int excl = incl - v;
        if (i < N) {
            int p = carry + excl;
            rowptr[i] = p;
            cursor[i] = p;
            dinv[i] = rsqrtf(1.0f + (float)v);
        }
        __syncthreads();
        if (threadIdx.x == 1023) carry += incl;
        __syncthreads();
    }
    if (threadIdx.x == 0) rowptr[N] = carry;
}

__global__ __launch_bounds__(256) void fill_csr(const int* __restrict__ row,
                                                const int* __restrict__ col,
                                                int* cursor, int* __restrict__ srow, int E) {
    int i = blockIdx.x * 256 + threadIdx.x;
    if (i < E) {
        int slot = atomicAdd(&cursor[col[i]], 1);
        srow[slot] = row[i];
    }
}

// ---------------- GEMM (fp32 vector ALU; no fp32 MFMA on CDNA4) ----------------
// G[n, :] = dinv[n] * (X[n, :] @ W)   (X: [N,128], W: [128,FOUT])
template <int FOUT>
__global__ __launch_bounds__(256) void gemm_scale(const float* __restrict__ X,
                                                  const float* __restrict__ W,
                                                  const float* __restrict__ dinv,
                                                  float* __restrict__ G, int N) {
    constexpr int ROWS = 32;
    constexpr int CT = FOUT / 4;     // threads along columns (each does 4 cols)
    constexpr int RT = 256 / CT;     // threads along rows
    constexpr int RPT = ROWS / RT;   // rows per thread
    __shared__ float Ws[KD][FOUT];
    __shared__ float Xs[ROWS][KD];

    int t = threadIdx.x;
    int row0 = blockIdx.x * ROWS;

    const float4* W4 = (const float4*)W;
    float4* Ws4 = (float4*)&Ws[0][0];
    for (int i = t; i < KD * FOUT / 4; i += 256) Ws4[i] = W4[i];

    const float4* X4 = (const float4*)X;
    float4* Xs4 = (float4*)&Xs[0][0];
    int nf4 = N * (KD / 4);
    for (int i = t; i < ROWS * KD / 4; i += 256) {
        int gi = row0 * (KD / 4) + i;
        Xs4[i] = (gi < nf4) ? X4[gi] : make_float4(0.f, 0.f, 0.f, 0.f);
    }
    __syncthreads();

    int ct = t % CT;
    int rt = t / CT;
    int c0 = ct * 4;
    float acc[RPT][4] = {};
#pragma unroll 4
    for (int k = 0; k < KD; ++k) {
        float4 wv = *(const float4*)&Ws[k][c0];
#pragma unroll
        for (int r = 0; r < RPT; ++r) {
            float xv = Xs[rt * RPT + r][k];
            acc[r][0] += xv * wv.x;
            acc[r][1] += xv * wv.y;
            acc[r][2] += xv * wv.z;
            acc[r][3] += xv * wv.w;
        }
    }
#pragma unroll
    for (int r = 0; r < RPT; ++r) {
        int rw = row0 + rt * RPT + r;
        if (rw < N) {
            float s = dinv[rw];
            float4 o = make_float4(acc[r][0] * s, acc[r][1] * s,
                                   acc[r][2] * s, acc[r][3] * s);
            *(float4*)&G[(size_t)rw * FOUT + c0] = o;
        }
    }
}

// ---------------- CSR gather + finalize (fused) ----------------
// One wave per destination node. acc = g[node] + sum_{e} g[srow[e]]; out = acc*dinv+b (relu?).
template <int F, bool RELU>
__global__ __launch_bounds__(256) void gather(const int* __restrict__ rowptr,
                                              const int* __restrict__ srow,
                                              const float* __restrict__ G,
                                              const float* __restrict__ dinv,
                                              const float* __restrict__ bias,
                                              float* __restrict__ O, int N) {
    int node = (blockIdx.x * 256 + threadIdx.x) >> 6;
    int lane = threadIdx.x & 63;
    if (node >= N) return;
    int beg = rowptr[node];
    int end = rowptr[node + 1];

    if constexpr (F == 128) {
        const float2* G2 = (const float2*)G;
        float2 acc = G2[(size_t)node * 64 + lane];  // self-loop
        int e = beg;
        for (; e + 1 < end; e += 2) {
            int r0 = srow[e];
            int r1 = srow[e + 1];
            float2 v0 = G2[(size_t)r0 * 64 + lane];
            float2 v1 = G2[(size_t)r1 * 64 + lane];
            acc.x += v0.x + v1.x;
            acc.y += v0.y + v1.y;
        }
        if (e < end) {
            int r0 = srow[e];
            float2 v0 = G2[(size_t)r0 * 64 + lane];
            acc.x += v0.x;
            acc.y += v0.y;
        }
        float s = dinv[node];
        float2 bv = ((const float2*)bias)[lane];
        float2 o;
        o.x = acc.x * s + bv.x;
        o.y = acc.y * s + bv.y;
        if (RELU) { o.x = fmaxf(o.x, 0.f); o.y = fmaxf(o.y, 0.f); }
        ((float2*)O)[(size_t)node * 64 + lane] = o;
    } else {
        float acc = G[(size_t)node * F + lane];  // self-loop (F==64: lane covers all)
        int e = beg;
        for (; e + 1 < end; e += 2) {
            int r0 = srow[e];
            int r1 = srow[e + 1];
            acc += G[(size_t)r0 * F + lane] + G[(size_t)r1 * F + lane];
        }
        if (e < end) acc += G[(size_t)srow[e] * F + lane];
        float o = acc * dinv[node] + bias[lane];
        if (RELU) o = fmaxf(o, 0.f);
        O[(size_t)node * F + lane] = o;
    }
}

extern "C" void kernel_launch(void* const* d_in, const int* in_sizes, int n_in,
                              void* d_out, int out_size, void* d_ws, size_t ws_size,
                              hipStream_t stream) {
    const float* x  = (const float*)d_in[0];
    const int*   ei = (const int*)d_in[1];   // int32
    const float* W1 = (const float*)d_in[2];
    const float* b1 = (const float*)d_in[3];
    const float* W2 = (const float*)d_in[4];
    const float* b2 = (const float*)d_in[5];
    float* out = (float*)d_out;

    int N = in_sizes[0] / 128;
    int E = in_sizes[1] / 2;
    const int* row = ei;       // edge_index[0]
    const int* col = ei + E;   // edge_index[1]

    // Workspace layout (<= ~56 MB; harness re-poisons each call, all init'd below)
    char* ws = (char*)d_ws;
    float* dinv   = (float*)(ws + 0x000000);            // 200 KB
    int*   cnt    = (int*)  (ws + 0x040000);            // 200 KB
    int*   rowptr = (int*)  (ws + 0x080000);            // 200 KB + 4
    int*   cursor = (int*)  (ws + 0x0C0000);            // 200 KB
    int*   srow   = (int*)  (ws + 0x100000);            // 3.2 MB
    float* bufA   = (float*)(ws + 0x440000);            // 25.6 MB
    float* bufB   = (float*)(ws + 0x1E00000);           // 25.6 MB

    int nb;
    // CSR build (shared by both layers) + dinv
    nb = (N + 255) / 256; hist_zero<<<nb, 256, 0, stream>>>(cnt, N);
    nb = (E + 255) / 256; hist<<<nb, 256, 0, stream>>>(col, cnt, E);
    scan_and_dinv<<<1, 1024, 0, stream>>>(cnt, rowptr, cursor, dinv, N);
    nb = (E + 255) / 256; fill_csr<<<nb, 256, 0, stream>>>(row, col, cursor, srow, E);

    // ---- layer 1 (F=128, relu) ----
    nb = (N + 31) / 32;
    gemm_scale<128><<<nb, 256, 0, stream>>>(x, W1, dinv, bufA, N);        // g1
    nb = (N + 3) / 4;  // one wave per node, 4 waves per block
    gather<128, true><<<nb, 256, 0, stream>>>(rowptr, srow, bufA, dinv, b1, bufB, N);  // h2

    // ---- layer 2 (F=64, no relu) ----
    nb = (N + 31) / 32;
    gemm_scale<64><<<nb, 256, 0, stream>>>(bufB, W2, dinv, bufA, N);      // g2
    nb = (N + 3) / 4;
    gather<64, false><<<nb, 256, 0, stream>>>(rowptr, srow, bufA, dinv, b2, out, N);
}

// Round 3
// 341.943 us; speedup vs baseline: 6.5626x; 1.2523x over previous
//
#include <hip/hip_runtime.h>

// GCN 2-layer forward for MI355X.
// out = D^-1/2 (A+I) D^-1/2 (X W) + b, twice, relu between.
// g = (X W) * dinv ; tmp[c] = g[c] + sum_{e: col_e=c} g[row_e] ; out = tmp*dinv + b.
// R2: CSR gather (no fp32 atomics). R3: parallel 3-phase scan (was 97us single-block).

constexpr int KD = 128;  // inner dim of both GEMMs (Fin = Fh = 128)

// ---------------- CSR build ----------------

__global__ __launch_bounds__(256) void hist_zero(int* cnt, int N) {
    int i = blockIdx.x * 256 + threadIdx.x;
    if (i < N) cnt[i] = 0;
}

__global__ __launch_bounds__(256) void hist(const int* __restrict__ col, int* cnt, int E) {
    int i = blockIdx.x * 256 + threadIdx.x;
    if (i < E) atomicAdd(&cnt[col[i]], 1);
}

// Phase 1: per-block (1024 elems) sum of cnt -> blockSums[b]
__global__ __launch_bounds__(256) void block_reduce(const int* __restrict__ cnt,
                                                    int* __restrict__ blockSums, int N) {
    __shared__ int wsum[4];
    int base = blockIdx.x * 1024 + threadIdx.x * 4;
    int s = 0;
#pragma unroll
    for (int j = 0; j < 4; ++j) {
        int i = base + j;
        if (i < N) s += cnt[i];
    }
    // wave reduce (64 lanes)
    for (int off = 32; off > 0; off >>= 1) s += __shfl_down(s, off, 64);
    int wave = threadIdx.x >> 6;
    if ((threadIdx.x & 63) == 0) wsum[wave] = s;
    __syncthreads();
    if (threadIdx.x == 0)
        blockSums[blockIdx.x] = wsum[0] + wsum[1] + wsum[2] + wsum[3];
}

// Phase 2: single wave exclusive-scans blockSums (NB <= 64) in place; rowptr[N]=E.
__global__ __launch_bounds__(64) void scan_block_sums(int* blockSums, int NB,
                                                      int* rowptr, int N, int E) {
    int lane = threadIdx.x;
    int v = (lane < NB) ? blockSums[lane] : 0;
    int s = v;
    for (int off = 1; off < 64; off <<= 1) {
        int t = __shfl_up(s, off, 64);
        if (lane >= off) s += t;
    }
    if (lane < NB) blockSums[lane] = s - v;  // exclusive
    if (lane == 0) rowptr[N] = E;
}

// Phase 3: per-block exclusive scan of 1024 cnt, + block offset; write rowptr/cursor/dinv.
__global__ __launch_bounds__(256) void block_scan_apply(const int* __restrict__ cnt,
                                                        const int* __restrict__ blockSums,
                                                        int* __restrict__ rowptr,
                                                        int* __restrict__ cursor,
                                                        float* __restrict__ dinv, int N) {
    __shared__ int tsum[256];
    int base = blockIdx.x * 1024 + threadIdx.x * 4;
    int v[4];
    int tot = 0;
#pragma unroll
    for (int j = 0; j < 4; ++j) {
        int i = base + j;
        v[j] = (i < N) ? cnt[i] : 0;
        tot += v[j];
    }
    tsum[threadIdx.x] = tot;
    __syncthreads();
    // Hillis-Steele inclusive scan over 256 thread totals
    for (int off = 1; off < 256; off <<= 1) {
        int t = (threadIdx.x >= off) ? tsum[threadIdx.x - off] : 0;
        __syncthreads();
        tsum[threadIdx.x] += t;
        __syncthreads();
    }
    int p = blockSums[blockIdx.x] + tsum[threadIdx.x] - tot;  // exclusive start
#pragma unroll
    for (int j = 0; j < 4; ++j) {
        int i = base + j;
        if (i < N) {
            rowptr[i] = p;
            cursor[i] = p;
            dinv[i] = rsqrtf(1.0f + (float)v[j]);
        }
        p += v[j];
    }
}

__global__ __launch_bounds__(256) void fill_csr(const int* __restrict__ row,
                                                const int* __restrict__ col,
                                                int* cursor, int* __restrict__ srow, int E) {
    int i = blockIdx.x * 256 + threadIdx.x;
    if (i < E) {
        int slot = atomicAdd(&cursor[col[i]], 1);
        srow[slot] = row[i];
    }
}

// ---------------- GEMM (fp32 vector ALU; no fp32 MFMA on CDNA4) ----------------
// G[n, :] = dinv[n] * (X[n, :] @ W)   (X: [N,128], W: [128,FOUT])
template <int FOUT>
__global__ __launch_bounds__(256) void gemm_scale(const float* __restrict__ X,
                                                  const float* __restrict__ W,
                                                  const float* __restrict__ dinv,
                                                  float* __restrict__ G, int N) {
    constexpr int ROWS = 32;
    constexpr int CT = FOUT / 4;     // threads along columns (each does 4 cols)
    constexpr int RT = 256 / CT;     // threads along rows
    constexpr int RPT = ROWS / RT;   // rows per thread
    __shared__ float Ws[KD][FOUT];
    __shared__ float Xs[ROWS][KD];

    int t = threadIdx.x;
    int row0 = blockIdx.x * ROWS;

    const float4* W4 = (const float4*)W;
    float4* Ws4 = (float4*)&Ws[0][0];
    for (int i = t; i < KD * FOUT / 4; i += 256) Ws4[i] = W4[i];

    const float4* X4 = (const float4*)X;
    float4* Xs4 = (float4*)&Xs[0][0];
    int nf4 = N * (KD / 4);
    for (int i = t; i < ROWS * KD / 4; i += 256) {
        int gi = row0 * (KD / 4) + i;
        Xs4[i] = (gi < nf4) ? X4[gi] : make_float4(0.f, 0.f, 0.f, 0.f);
    }
    __syncthreads();

    int ct = t % CT;
    int rt = t / CT;
    int c0 = ct * 4;
    float acc[RPT][4] = {};
#pragma unroll 4
    for (int k = 0; k < KD; ++k) {
        float4 wv = *(const float4*)&Ws[k][c0];
#pragma unroll
        for (int r = 0; r < RPT; ++r) {
            float xv = Xs[rt * RPT + r][k];
            acc[r][0] += xv * wv.x;
            acc[r][1] += xv * wv.y;
            acc[r][2] += xv * wv.z;
            acc[r][3] += xv * wv.w;
        }
    }
#pragma unroll
    for (int r = 0; r < RPT; ++r) {
        int rw = row0 + rt * RPT + r;
        if (rw < N) {
            float s = dinv[rw];
            float4 o = make_float4(acc[r][0] * s, acc[r][1] * s,
                                   acc[r][2] * s, acc[r][3] * s);
            *(float4*)&G[(size_t)rw * FOUT + c0] = o;
        }
    }
}

// ---------------- CSR gather + finalize (fused) ----------------
// One wave per destination node. acc = g[node] + sum_{e} g[srow[e]]; out = acc*dinv+b (relu?).
template <int F, bool RELU>
__global__ __launch_bounds__(256) void gather(const int* __restrict__ rowptr,
                                              const int* __restrict__ srow,
                                              const float* __restrict__ G,
                                              const float* __restrict__ dinv,
                                              const float* __restrict__ bias,
                                              float* __restrict__ O, int N) {
    int node = (blockIdx.x * 256 + threadIdx.x) >> 6;
    int lane = threadIdx.x & 63;
    if (node >= N) return;
    int beg = rowptr[node];
    int end = rowptr[node + 1];

    if constexpr (F == 128) {
        const float2* G2 = (const float2*)G;
        float2 acc = G2[(size_t)node * 64 + lane];  // self-loop
        int e = beg;
        for (; e + 1 < end; e += 2) {
            int r0 = srow[e];
            int r1 = srow[e + 1];
            float2 v0 = G2[(size_t)r0 * 64 + lane];
            float2 v1 = G2[(size_t)r1 * 64 + lane];
            acc.x += v0.x + v1.x;
            acc.y += v0.y + v1.y;
        }
        if (e < end) {
            int r0 = srow[e];
            float2 v0 = G2[(size_t)r0 * 64 + lane];
            acc.x += v0.x;
            acc.y += v0.y;
        }
        float s = dinv[node];
        float2 bv = ((const float2*)bias)[lane];
        float2 o;
        o.x = acc.x * s + bv.x;
        o.y = acc.y * s + bv.y;
        if (RELU) { o.x = fmaxf(o.x, 0.f); o.y = fmaxf(o.y, 0.f); }
        ((float2*)O)[(size_t)node * 64 + lane] = o;
    } else {
        float acc = G[(size_t)node * F + lane];  // self-loop (F==64: lane covers all)
        int e = beg;
        for (; e + 1 < end; e += 2) {
            int r0 = srow[e];
            int r1 = srow[e + 1];
            acc += G[(size_t)r0 * F + lane] + G[(size_t)r1 * F + lane];
        }
        if (e < end) acc += G[(size_t)srow[e] * F + lane];
        float o = acc * dinv[node] + bias[lane];
        if (RELU) o = fmaxf(o, 0.f);
        O[(size_t)node * F + lane] = o;
    }
}

extern "C" void kernel_launch(void* const* d_in, const int* in_sizes, int n_in,
                              void* d_out, int out_size, void* d_ws, size_t ws_size,
                              hipStream_t stream) {
    const float* x  = (const float*)d_in[0];
    const int*   ei = (const int*)d_in[1];   // int32
    const float* W1 = (const float*)d_in[2];
    const float* b1 = (const float*)d_in[3];
    const float* W2 = (const float*)d_in[4];
    const float* b2 = (const float*)d_in[5];
    float* out = (float*)d_out;

    int N = in_sizes[0] / 128;
    int E = in_sizes[1] / 2;
    const int* row = ei;       // edge_index[0]
    const int* col = ei + E;   // edge_index[1]

    // Workspace layout (<= ~56 MB; harness re-poisons each call, all init'd below)
    char* ws = (char*)d_ws;
    float* dinv   = (float*)(ws + 0x000000);            // 200 KB
    int*   cnt    = (int*)  (ws + 0x040000);            // 200 KB
    int*   rowptr = (int*)  (ws + 0x080000);            // 200 KB + 4
    int*   cursor = (int*)  (ws + 0x0C0000);            // 200 KB
    int*   bsums  = (int*)  (ws + 0x0FC000);            // 49 ints (blockSums)
    int*   srow   = (int*)  (ws + 0x100000);            // 3.2 MB
    float* bufA   = (float*)(ws + 0x440000);            // 25.6 MB
    float* bufB   = (float*)(ws + 0x1E00000);           // 25.6 MB

    int NB_SCAN = (N + 1023) / 1024;  // 49 for N=50000 (<= 64 for phase-2 wave scan)

    int nb;
    // CSR build (shared by both layers) + dinv
    nb = (N + 255) / 256; hist_zero<<<nb, 256, 0, stream>>>(cnt, N);
    nb = (E + 255) / 256; hist<<<nb, 256, 0, stream>>>(col, cnt, E);
    block_reduce<<<NB_SCAN, 256, 0, stream>>>(cnt, bsums, N);
    scan_block_sums<<<1, 64, 0, stream>>>(bsums, NB_SCAN, rowptr, N, E);
    block_scan_apply<<<NB_SCAN, 256, 0, stream>>>(cnt, bsums, rowptr, cursor, dinv, N);
    nb = (E + 255) / 256; fill_csr<<<nb, 256, 0, stream>>>(row, col, cursor, srow, E);

    // ---- layer 1 (F=128, relu) ----
    nb = (N + 31) / 32;
    gemm_scale<128><<<nb, 256, 0, stream>>>(x, W1, dinv, bufA, N);        // g1
    nb = (N + 3) / 4;  // one wave per node, 4 waves per block
    gather<128, true><<<nb, 256, 0, stream>>>(rowptr, srow, bufA, dinv, b1, bufB, N);  // h2

    // ---- layer 2 (F=64, no relu) ----
    nb = (N + 31) / 32;
    gemm_scale<64><<<nb, 256, 0, stream>>>(bufB, W2, dinv, bufA, N);      // g2
    nb = (N + 3) / 4;
    gather<64, false><<<nb, 256, 0, stream>>>(rowptr, srow, bufA, dinv, b2, out, N);
}

// Round 4
// 290.814 us; speedup vs baseline: 7.7164x; 1.1758x over previous
//
#include <hip/hip_runtime.h>

// GCN 2-layer forward for MI355X.
// out = D^-1/2 (A+I) D^-1/2 (X W) + b, twice, relu between.
// g = (X W) * dinv ; tmp[c] = g[c] + sum_{e: col_e=c} g[row_e] ; out = tmp*dinv + b.
// R2: CSR gather (no fp32 atomics). R3: parallel 3-phase scan.
// R4: g stored as bf16 -> halves edge-gather traffic (the 42%-of-HBM bottleneck).
//     Accumulation/GEMM/bias/output all stay fp32; only the gather operand is bf16.

constexpr int KD = 128;  // inner dim of both GEMMs (Fin = Fh = 128)

// ---------------- bf16 helpers (storage = ushort, math = fp32) ----------------

__device__ __forceinline__ unsigned short f2bf(float f) {
    unsigned int u = __float_as_uint(f);
    u = (u + 0x7fffu + ((u >> 16) & 1u)) >> 16;  // round-to-nearest-even
    return (unsigned short)u;
}

__device__ __forceinline__ float2 bfpair(unsigned int u) {
    float2 f;
    f.x = __uint_as_float(u << 16);          // low short = first feature
    f.y = __uint_as_float(u & 0xffff0000u);  // high short = second feature
    return f;
}

// ---------------- CSR build ----------------

__global__ __launch_bounds__(256) void hist_zero(int* cnt, int N) {
    int i = blockIdx.x * 256 + threadIdx.x;
    if (i < N) cnt[i] = 0;
}

__global__ __launch_bounds__(256) void hist(const int* __restrict__ col, int* cnt, int E) {
    int i = blockIdx.x * 256 + threadIdx.x;
    if (i < E) atomicAdd(&cnt[col[i]], 1);
}

// Phase 1: per-block (1024 elems) sum of cnt -> blockSums[b]
__global__ __launch_bounds__(256) void block_reduce(const int* __restrict__ cnt,
                                                    int* __restrict__ blockSums, int N) {
    __shared__ int wsum[4];
    int base = blockIdx.x * 1024 + threadIdx.x * 4;
    int s = 0;
#pragma unroll
    for (int j = 0; j < 4; ++j) {
        int i = base + j;
        if (i < N) s += cnt[i];
    }
    for (int off = 32; off > 0; off >>= 1) s += __shfl_down(s, off, 64);
    int wave = threadIdx.x >> 6;
    if ((threadIdx.x & 63) == 0) wsum[wave] = s;
    __syncthreads();
    if (threadIdx.x == 0)
        blockSums[blockIdx.x] = wsum[0] + wsum[1] + wsum[2] + wsum[3];
}

// Phase 2: single wave exclusive-scans blockSums (NB <= 64) in place; rowptr[N]=E.
__global__ __launch_bounds__(64) void scan_block_sums(int* blockSums, int NB,
                                                      int* rowptr, int N, int E) {
    int lane = threadIdx.x;
    int v = (lane < NB) ? blockSums[lane] : 0;
    int s = v;
    for (int off = 1; off < 64; off <<= 1) {
        int t = __shfl_up(s, off, 64);
        if (lane >= off) s += t;
    }
    if (lane < NB) blockSums[lane] = s - v;  // exclusive
    if (lane == 0) rowptr[N] = E;
}

// Phase 3: per-block exclusive scan of 1024 cnt, + block offset; write rowptr/cursor/dinv.
__global__ __launch_bounds__(256) void block_scan_apply(const int* __restrict__ cnt,
                                                        const int* __restrict__ blockSums,
                                                        int* __restrict__ rowptr,
                                                        int* __restrict__ cursor,
                                                        float* __restrict__ dinv, int N) {
    __shared__ int tsum[256];
    int base = blockIdx.x * 1024 + threadIdx.x * 4;
    int v[4];
    int tot = 0;
#pragma unroll
    for (int j = 0; j < 4; ++j) {
        int i = base + j;
        v[j] = (i < N) ? cnt[i] : 0;
        tot += v[j];
    }
    tsum[threadIdx.x] = tot;
    __syncthreads();
    for (int off = 1; off < 256; off <<= 1) {
        int t = (threadIdx.x >= off) ? tsum[threadIdx.x - off] : 0;
        __syncthreads();
        tsum[threadIdx.x] += t;
        __syncthreads();
    }
    int p = blockSums[blockIdx.x] + tsum[threadIdx.x] - tot;  // exclusive start
#pragma unroll
    for (int j = 0; j < 4; ++j) {
        int i = base + j;
        if (i < N) {
            rowptr[i] = p;
            cursor[i] = p;
            dinv[i] = rsqrtf(1.0f + (float)v[j]);
        }
        p += v[j];
    }
}

__global__ __launch_bounds__(256) void fill_csr(const int* __restrict__ row,
                                                const int* __restrict__ col,
                                                int* cursor, int* __restrict__ srow, int E) {
    int i = blockIdx.x * 256 + threadIdx.x;
    if (i < E) {
        int slot = atomicAdd(&cursor[col[i]], 1);
        srow[slot] = row[i];
    }
}

// ---------------- GEMM (fp32 vector ALU; no fp32 MFMA on CDNA4) ----------------
// G[n, :] = bf16( dinv[n] * (X[n, :] @ W) )   (X: [N,128] fp32, W: [128,FOUT] fp32)
template <int FOUT>
__global__ __launch_bounds__(256) void gemm_scale(const float* __restrict__ X,
                                                  const float* __restrict__ W,
                                                  const float* __restrict__ dinv,
                                                  unsigned short* __restrict__ G, int N) {
    constexpr int ROWS = 32;
    constexpr int CT = FOUT / 4;     // threads along columns (each does 4 cols)
    constexpr int RT = 256 / CT;     // threads along rows
    constexpr int RPT = ROWS / RT;   // rows per thread
    __shared__ float Ws[KD][FOUT];
    __shared__ float Xs[ROWS][KD];

    int t = threadIdx.x;
    int row0 = blockIdx.x * ROWS;

    const float4* W4 = (const float4*)W;
    float4* Ws4 = (float4*)&Ws[0][0];
    for (int i = t; i < KD * FOUT / 4; i += 256) Ws4[i] = W4[i];

    const float4* X4 = (const float4*)X;
    float4* Xs4 = (float4*)&Xs[0][0];
    int nf4 = N * (KD / 4);
    for (int i = t; i < ROWS * KD / 4; i += 256) {
        int gi = row0 * (KD / 4) + i;
        Xs4[i] = (gi < nf4) ? X4[gi] : make_float4(0.f, 0.f, 0.f, 0.f);
    }
    __syncthreads();

    int ct = t % CT;
    int rt = t / CT;
    int c0 = ct * 4;
    float acc[RPT][4] = {};
#pragma unroll 4
    for (int k = 0; k < KD; ++k) {
        float4 wv = *(const float4*)&Ws[k][c0];
#pragma unroll
        for (int r = 0; r < RPT; ++r) {
            float xv = Xs[rt * RPT + r][k];
            acc[r][0] += xv * wv.x;
            acc[r][1] += xv * wv.y;
            acc[r][2] += xv * wv.z;
            acc[r][3] += xv * wv.w;
        }
    }
#pragma unroll
    for (int r = 0; r < RPT; ++r) {
        int rw = row0 + rt * RPT + r;
        if (rw < N) {
            float s = dinv[rw];
            ushort4 o;
            o.x = f2bf(acc[r][0] * s);
            o.y = f2bf(acc[r][1] * s);
            o.z = f2bf(acc[r][2] * s);
            o.w = f2bf(acc[r][3] * s);
            *(ushort4*)&G[(size_t)rw * FOUT + c0] = o;
        }
    }
}

// ---------------- CSR gather + finalize (fused), bf16 operand ----------------
// F=128: one wave per node, lane holds 2 features (ushort2 = 1 dword load/row).
template <bool RELU>
__global__ __launch_bounds__(256) void gather128(const int* __restrict__ rowptr,
                                                 const int* __restrict__ srow,
                                                 const unsigned int* __restrict__ G,  // bf16x2
                                                 const float* __restrict__ dinv,
                                                 const float* __restrict__ bias,
                                                 float* __restrict__ O, int N) {
    int node = (blockIdx.x * 256 + threadIdx.x) >> 6;
    int lane = threadIdx.x & 63;
    if (node >= N) return;
    int beg = rowptr[node];
    int end = rowptr[node + 1];

    float2 s0 = bfpair(G[(size_t)node * 64 + lane]);  // self-loop
    float ax = s0.x, ay = s0.y;

    int e = beg;
    for (; e + 3 < end; e += 4) {
        int r0 = srow[e], r1 = srow[e + 1], r2 = srow[e + 2], r3 = srow[e + 3];
        float2 v0 = bfpair(G[(size_t)r0 * 64 + lane]);
        float2 v1 = bfpair(G[(size_t)r1 * 64 + lane]);
        float2 v2 = bfpair(G[(size_t)r2 * 64 + lane]);
        float2 v3 = bfpair(G[(size_t)r3 * 64 + lane]);
        ax += (v0.x + v1.x) + (v2.x + v3.x);
        ay += (v0.y + v1.y) + (v2.y + v3.y);
    }
    for (; e < end; ++e) {
        float2 v = bfpair(G[(size_t)srow[e] * 64 + lane]);
        ax += v.x;
        ay += v.y;
    }
    float s = dinv[node];
    float2 bv = ((const float2*)bias)[lane];
    float ox = ax * s + bv.x;
    float oy = ay * s + bv.y;
    if (RELU) { ox = fmaxf(ox, 0.f); oy = fmaxf(oy, 0.f); }
    float2 o = make_float2(ox, oy);
    ((float2*)O)[(size_t)node * 64 + lane] = o;
}

// F=64: half-wave per node (32 lanes x ushort2 = 128B row), 2 nodes per wave.
template <bool RELU>
__global__ __launch_bounds__(256) void gather64(const int* __restrict__ rowptr,
                                                const int* __restrict__ srow,
                                                const unsigned int* __restrict__ G,  // bf16x2
                                                const float* __restrict__ dinv,
                                                const float* __restrict__ bias,
                                                float* __restrict__ O, int N) {
    int tid = blockIdx.x * 256 + threadIdx.x;
    int node = tid >> 5;          // half-wave per node
    int lane = threadIdx.x & 31;
    if (node >= N) return;
    int beg = rowptr[node];
    int end = rowptr[node + 1];

    float2 s0 = bfpair(G[(size_t)node * 32 + lane]);  // self-loop
    float ax = s0.x, ay = s0.y;

    int e = beg;
    for (; e + 3 < end; e += 4) {
        int r0 = srow[e], r1 = srow[e + 1], r2 = srow[e + 2], r3 = srow[e + 3];
        float2 v0 = bfpair(G[(size_t)r0 * 32 + lane]);
        float2 v1 = bfpair(G[(size_t)r1 * 32 + lane]);
        float2 v2 = bfpair(G[(size_t)r2 * 32 + lane]);
        float2 v3 = bfpair(G[(size_t)r3 * 32 + lane]);
        ax += (v0.x + v1.x) + (v2.x + v3.x);
        ay += (v0.y + v1.y) + (v2.y + v3.y);
    }
    for (; e < end; ++e) {
        float2 v = bfpair(G[(size_t)srow[e] * 32 + lane]);
        ax += v.x;
        ay += v.y;
    }
    float s = dinv[node];
    float2 bv = ((const float2*)bias)[lane];
    float ox = ax * s + bv.x;
    float oy = ay * s + bv.y;
    if (RELU) { ox = fmaxf(ox, 0.f); oy = fmaxf(oy, 0.f); }
    float2 o = make_float2(ox, oy);
    ((float2*)O)[(size_t)node * 32 + lane] = o;
}

extern "C" void kernel_launch(void* const* d_in, const int* in_sizes, int n_in,
                              void* d_out, int out_size, void* d_ws, size_t ws_size,
                              hipStream_t stream) {
    const float* x  = (const float*)d_in[0];
    const int*   ei = (const int*)d_in[1];   // int32
    const float* W1 = (const float*)d_in[2];
    const float* b1 = (const float*)d_in[3];
    const float* W2 = (const float*)d_in[4];
    const float* b2 = (const float*)d_in[5];
    float* out = (float*)d_out;

    int N = in_sizes[0] / 128;
    int E = in_sizes[1] / 2;
    const int* row = ei;       // edge_index[0]
    const int* col = ei + E;   // edge_index[1]

    // Workspace layout (all regions written before read each call)
    char* ws = (char*)d_ws;
    float* dinv   = (float*)(ws + 0x000000);             // 200 KB
    int*   cnt    = (int*)  (ws + 0x040000);             // 200 KB
    int*   rowptr = (int*)  (ws + 0x080000);             // 200 KB + 4
    int*   cursor = (int*)  (ws + 0x0C0000);             // 200 KB
    int*   bsums  = (int*)  (ws + 0x0FC000);             // 49 ints
    int*   srow   = (int*)  (ws + 0x100000);             // 3.2 MB
    unsigned short* g1 = (unsigned short*)(ws + 0x440000);   // N*128 bf16 = 12.8 MB
    float* h2     = (float*)(ws + 0x1200000);            // N*128 fp32 = 25.6 MB
    unsigned short* g2 = (unsigned short*)(ws + 0x2C00000);  // N*64 bf16 = 6.4 MB

    int NB_SCAN = (N + 1023) / 1024;  // 49 for N=50000 (<=64 for phase-2 wave scan)

    int nb;
    // CSR build (shared by both layers) + dinv
    nb = (N + 255) / 256; hist_zero<<<nb, 256, 0, stream>>>(cnt, N);
    nb = (E + 255) / 256; hist<<<nb, 256, 0, stream>>>(col, cnt, E);
    block_reduce<<<NB_SCAN, 256, 0, stream>>>(cnt, bsums, N);
    scan_block_sums<<<1, 64, 0, stream>>>(bsums, NB_SCAN, rowptr, N, E);
    block_scan_apply<<<NB_SCAN, 256, 0, stream>>>(cnt, bsums, rowptr, cursor, dinv, N);
    nb = (E + 255) / 256; fill_csr<<<nb, 256, 0, stream>>>(row, col, cursor, srow, E);

    // ---- layer 1 (F=128, relu) ----
    nb = (N + 31) / 32;
    gemm_scale<128><<<nb, 256, 0, stream>>>(x, W1, dinv, g1, N);
    nb = (N + 3) / 4;  // one wave per node
    gather128<true><<<nb, 256, 0, stream>>>(rowptr, srow, (const unsigned int*)g1,
                                            dinv, b1, h2, N);

    // ---- layer 2 (F=64, no relu) ----
    nb = (N + 31) / 32;
    gemm_scale<64><<<nb, 256, 0, stream>>>(h2, W2, dinv, g2, N);
    nb = (N + 7) / 8;  // half-wave per node
    gather64<false><<<nb, 256, 0, stream>>>(rowptr, srow, (const unsigned int*)g2,
                                            dinv, b2, out, N);
}